// Round 15
// baseline (158.397 us; speedup 1.0000x reference)
//
#include <hip/hip_runtime.h>

#define T_DIM 720
#define B_DIM 50000
#define BPAD 50048

#define OFF_SEAS (T_DIM * B_DIM)                  /* 36,000,000 */
#define OFF_MSLD (OFF_SEAS + 727 * B_DIM)         /* 72,350,000 */
#define N_MSLD 718

#define NBLK1 782                                 /* pass-1 blocks (1 wave) */
#define NSEG 4
#define NBLK2 (NSEG * NBLK1)                      /* 3128 pass-2 blocks */
#define STRIP 184                                 /* per-strip floats */
#define LN2_SQ 0.4804530139182014f                /* (ln 2)^2 */

/* ws layout (floats): [0, 3128*184) partial strips; ckpt at 600000:
   3 slots x 9 fields x BPAD = 1,351,296 -> total ~7.9 MB */
#define WS_CKPT 600000

// Wave64 sum via DPP: row_shr 1/2/4/8, row_bcast 15/31. Result in lane 63.
__device__ __forceinline__ float dpp_sum64(float v) {
#define DPP_ADD_STAGE(CTRL, RMASK)                                             \
  v += __int_as_float(__builtin_amdgcn_update_dpp(0, __float_as_int(v),        \
                                                  CTRL, RMASK, 0xf, false));
  DPP_ADD_STAGE(0x111, 0xf)
  DPP_ADD_STAGE(0x112, 0xf)
  DPP_ADD_STAGE(0x114, 0xf)
  DPP_ADD_STAGE(0x118, 0xf)
  DPP_ADD_STAGE(0x142, 0xa)
  DPP_ADD_STAGE(0x143, 0xc)
#undef DPP_ADD_STAGE
  return v;
}

#define PIN7(QB)                                                               \
  asm volatile("" : "+v"(QB[0]), "+v"(QB[1]), "+v"(QB[2]), "+v"(QB[3]),        \
                    "+v"(QB[4]), "+v"(QB[5]), "+v"(QB[6]));

// ---------------- Pass 1: state-only recurrence + checkpoints ----------------

#define P1_PREFETCH(QB, G)                                                     \
  {                                                                            \
    int tp = 1 + 7 * (G);                                                      \
    _Pragma("unroll") for (int j = 0; j < 7; ++j) {                            \
      int r = tp + j;                                                          \
      r = r > 719 ? 719 : r;                                                   \
      QB[j] = train[r * B_DIM + bc];                                           \
    }                                                                          \
  }

// One state-only group: 14 divides + 14 FMAs, no logs/stores. Checkpoint after
// groups 26/52/78 (t=182/364/546): buf[7], lev, levp (lev at t-1).
#define P1_BODY(QB, QPIN, QLD)                                                 \
  {                                                                            \
    P1_PREFETCH(QLD, g + 3)                                                    \
    PIN7(QPIN)                                                                 \
    float xds[7], nlv[7];                                                      \
    _Pragma("unroll") for (int j = 0; j < 7; ++j)                              \
        xds[j] = __fdividef(QB[j], buf[j]);                                    \
    nlv[0] = fmaf(lsm, xds[0], olm * lev);                                     \
    _Pragma("unroll") for (int j = 1; j < 7; ++j)                              \
        nlv[j] = fmaf(lsm, xds[j], olm * nlv[j - 1]);                          \
    _Pragma("unroll") for (int j = 0; j < 7; ++j)                              \
        buf[j] = fmaf(ssm, __fdividef(QB[j], nlv[j]), osm * buf[j]);           \
    lev = nlv[6];                                                              \
    ++g;                                                                       \
    if (g == 26 || g == 52 || g == 78) {                                       \
      int slot = (g == 26) ? 0 : ((g == 52) ? 1 : 2);                          \
      float* cp = ckpt + (size_t)slot * 9 * BPAD + b;                          \
      _Pragma("unroll") for (int j = 0; j < 7; ++j) cp[j * BPAD] = buf[j];     \
      cp[7 * BPAD] = lev;                                                      \
      cp[8 * BPAD] = nlv[5];                                                   \
    }                                                                          \
  }

__global__ __launch_bounds__(64) void esrnn_pass1(
    const float* __restrict__ train, const float* __restrict__ lev_sms,
    const float* __restrict__ seas_sms, const float* __restrict__ init_seas_in,
    float* __restrict__ ckpt) {
  int b = blockIdx.x * 64 + threadIdx.x;
  int bc = b < B_DIM ? b : (B_DIM - 1);

  float lsm = 1.0f / (1.0f + __expf(-lev_sms[bc]));
  float ssm = 1.0f / (1.0f + __expf(-seas_sms[bc]));
  float olm = 1.0f - lsm, osm = 1.0f - ssm;

  float is[7];
#pragma unroll
  for (int j = 0; j < 7; ++j) is[j] = __expf(init_seas_in[bc * 7 + j]);
  float lev = __fdividef(train[bc], is[0]);

  float buf[7];
#pragma unroll
  for (int j = 0; j < 6; ++j) buf[j] = is[j + 1];
  buf[6] = is[0];

  float xa[7], xb[7], xc[7], xd[7];
  int g = 0;
  P1_PREFETCH(xa, 0)
  P1_PREFETCH(xb, 1)
  P1_PREFETCH(xc, 2)
  for (int k = 0; k < 20; ++k) {  // 80 groups (78 needed; 2 spare harmless)
    P1_BODY(xa, xb, xd)
    P1_BODY(xb, xc, xa)
    P1_BODY(xc, xd, xb)
    P1_BODY(xd, xa, xc)
  }
}

// ---------------- Pass 2: 4 segments, full outputs ----------------

#define P2_PREFETCH(QB, LG)                                                    \
  {                                                                            \
    int tp = t0 + 7 * (LG);                                                    \
    _Pragma("unroll") for (int j = 0; j < 7; ++j) {                            \
      int r = tp + j;                                                          \
      r = r > 719 ? 719 : r;                                                   \
      QB[j] = train[r * B_DIM + bc];                                           \
    }                                                                          \
  }

// Full group (R14 structure); LDS slot = 7*lg + j + 1 (local to segment).
#define P2_GROUP_N(QB, NS)                                                     \
  {                                                                            \
    float xds[7], nlv[7], llv[7];                                              \
    _Pragma("unroll") for (int j = 0; j < (NS); ++j)                           \
        xds[j] = __fdividef(QB[j], buf[j]);                                    \
    nlv[0] = fmaf(lsm, xds[0], olm * lev);                                     \
    _Pragma("unroll") for (int j = 1; j < (NS); ++j)                           \
        nlv[j] = fmaf(lsm, xds[j], olm * nlv[j - 1]);                          \
    _Pragma("unroll") for (int j = 0; j < (NS); ++j)                           \
        llv[j] = __log2f(nlv[j]);                                              \
    _Pragma("unroll") for (int j = 0; j < (NS); ++j)                           \
        buf[j] = fmaf(ssm, __fdividef(QB[j], nlv[j]), osm * buf[j]);           \
    if (valid) {                                                               \
      _Pragma("unroll") for (int j = 0; j < (NS); ++j) {                       \
        *(float*)(lbase + boff + (unsigned)(j * B_DIM * 4)) = nlv[j];          \
        *(float*)(sbase + boff + (unsigned)(j * B_DIM * 4)) = buf[j];          \
      }                                                                        \
    }                                                                          \
    boff += (NS)*B_DIM * 4;                                                    \
    float sqv[7];                                                              \
    {                                                                          \
      float ld0 = llv[0] - llev;                                               \
      float d0 = ld0 - pld;                                                    \
      sqv[0] = valid ? d0 * d0 : 0.0f;                                         \
      float ldp = ld0;                                                         \
      _Pragma("unroll") for (int j = 1; j < (NS); ++j) {                       \
        float ld = llv[j] - llv[j - 1];                                        \
        float d = ld - ldp;                                                    \
        sqv[j] = valid ? d * d : 0.0f;                                         \
        ldp = ld;                                                              \
      }                                                                        \
      pld = ldp;                                                               \
    }                                                                          \
    llev = llv[(NS)-1];                                                        \
    lev = nlv[(NS)-1];                                                         \
    _Pragma("unroll") for (int j = 0; j < (NS); ++j)                           \
        sqv[j] = dpp_sum64(sqv[j]);                                            \
    if (lane == 63) {                                                          \
      _Pragma("unroll") for (int j = 0; j < (NS); ++j)                         \
          lds_p[7 * lg + j + 1] = sqv[j];                                      \
    }                                                                          \
  }

#define P2_BODY(QB, QPIN, QLD)                                                 \
  {                                                                            \
    P2_PREFETCH(QLD, lg + 3)                                                   \
    PIN7(QPIN)                                                                 \
    P2_GROUP_N(QB, 7)                                                          \
    ++lg;                                                                      \
  }

__global__ __launch_bounds__(64) void esrnn_pass2(
    const float* __restrict__ train, const float* __restrict__ lev_sms,
    const float* __restrict__ seas_sms, const float* __restrict__ init_seas_in,
    float* __restrict__ levs_out, float* __restrict__ seas_out,
    float* __restrict__ partial, const float* __restrict__ ckpt) {
  __shared__ float lds_p[STRIP];

  int wid = blockIdx.x;
  int seg = wid / NBLK1;
  int sblk = wid - seg * NBLK1;
  int lane = threadIdx.x;
  int b = sblk * 64 + lane;
  bool valid = (b < B_DIM);
  int bc = valid ? b : (B_DIM - 1);
  int t0 = 1 + 182 * seg;  // 1, 183, 365, 547

  float lsm = 1.0f / (1.0f + __expf(-lev_sms[bc]));
  float ssm = 1.0f / (1.0f + __expf(-seas_sms[bc]));
  float olm = 1.0f - lsm, osm = 1.0f - ssm;

  float buf[7], lev, llev, pld;
  if (seg == 0) {
    float is[7];
#pragma unroll
    for (int j = 0; j < 7; ++j) is[j] = __expf(init_seas_in[bc * 7 + j]);
    lev = __fdividef(train[bc], is[0]);
    if (valid) {
      levs_out[b] = lev;
#pragma unroll
      for (int j = 0; j < 7; ++j) seas_out[j * B_DIM + b] = is[j];
      seas_out[7 * B_DIM + b] = is[0];
    }
#pragma unroll
    for (int j = 0; j < 6; ++j) buf[j] = is[j + 1];
    buf[6] = is[0];
    llev = __log2f(lev);
    pld = 0.0f;
  } else {
    const float* cp = ckpt + (size_t)(seg - 1) * 9 * BPAD + b;
#pragma unroll
    for (int j = 0; j < 7; ++j) buf[j] = cp[j * BPAD];
    lev = cp[7 * BPAD];
    float levp = cp[8 * BPAD];
    llev = __log2f(lev);
    pld = llev - __log2f(levp);
  }

  char* lbase = (char*)levs_out + (size_t)t0 * B_DIM * 4;
  char* sbase = (char*)seas_out + (size_t)(t0 + 7) * B_DIM * 4;
  unsigned int boff = (unsigned)b * 4u;

  float xa[7], xb[7], xc[7], xd[7];
  int lg = 0;
  P2_PREFETCH(xa, 0)
  P2_PREFETCH(xb, 1)
  P2_PREFETCH(xc, 2)
  for (int k = 0; k < 6; ++k) {  // local groups 0..23
    P2_BODY(xa, xb, xd)
    P2_BODY(xb, xc, xa)
    P2_BODY(xc, xd, xb)
    P2_BODY(xd, xa, xc)
  }
  if (seg < 3) {  // groups 24, 25 -> 26 x 7 = 182 steps
    P2_BODY(xa, xb, xd)
    P2_BODY(xb, xc, xa)
  } else {  // tail 5 steps: t = 715..719 in xa (lg = 24)
    P2_GROUP_N(xa, 5)
  }

  __syncthreads();  // drain LDS writes (single-wave block)
  float* strip = partial + (size_t)wid * STRIP;
  for (int i = lane; i < STRIP; i += 64) strip[i] = lds_p[i];
}

// ---------------- Reduce ----------------

__global__ __launch_bounds__(64) void esrnn_reduce2(
    const float* __restrict__ partial, float* __restrict__ msld) {
  int row = blockIdx.x;  // 0..717
  int lane = threadIdx.x;
  int t = row + 2;
  int s = (t - 1) / 182;
  if (s > 3) s = 3;
  int i = t - (1 + 182 * s) + 1;
  const float* base = partial + (size_t)s * NBLK1 * STRIP + i;
  float sum = 0.0f;
  for (int q = lane; q < NBLK1; q += 64) sum += base[(size_t)q * STRIP];
  float tot = dpp_sum64(sum);
  if (lane == 63) msld[row] = tot * (LN2_SQ / (float)B_DIM);
}

extern "C" void kernel_launch(void* const* d_in, const int* in_sizes, int n_in,
                              void* d_out, int out_size, void* d_ws,
                              size_t ws_size, hipStream_t stream) {
  const float* train = (const float*)d_in[0];
  const float* lev_sms = (const float*)d_in[1];
  const float* seas_sms = (const float*)d_in[2];
  const float* init_seas = (const float*)d_in[3];

  float* out = (float*)d_out;
  float* levs = out;
  float* seas = out + OFF_SEAS;
  float* msld = out + OFF_MSLD;
  float* partial = (float*)d_ws;
  float* ckpt = (float*)d_ws + WS_CKPT;

  esrnn_pass1<<<NBLK1, 64, 0, stream>>>(train, lev_sms, seas_sms, init_seas,
                                        ckpt);
  esrnn_pass2<<<NBLK2, 64, 0, stream>>>(train, lev_sms, seas_sms, init_seas,
                                        levs, seas, partial, ckpt);
  esrnn_reduce2<<<N_MSLD, 64, 0, stream>>>(partial, msld);
}

// Round 16
// 129.521 us; speedup vs baseline: 1.2229x; 1.2229x over previous
//
#include <hip/hip_runtime.h>

#define T_DIM 720
#define B_DIM 50000

#define OFF_SEAS (T_DIM * B_DIM)                  /* 36,000,000 */
#define OFF_MSLD (OFF_SEAS + 727 * B_DIM)         /* 72,350,000 */
#define N_MSLD 718

#define NBLK 782                                  /* blocks; 128 thr = 2 waves */
#define NW NBLK
#define LN2_SQ 0.4804530139182014f                /* (ln 2)^2 */

typedef float v2f __attribute__((ext_vector_type(2)));

// Wave64 sum via DPP: row_shr 1/2/4/8, row_bcast 15/31. Result in lane 63.
__device__ __forceinline__ float dpp_sum64(float v) {
#define DPP_ADD_STAGE(CTRL, RMASK)                                             \
  v += __int_as_float(__builtin_amdgcn_update_dpp(0, __float_as_int(v),        \
                                                  CTRL, RMASK, 0xf, false));
  DPP_ADD_STAGE(0x111, 0xf)
  DPP_ADD_STAGE(0x112, 0xf)
  DPP_ADD_STAGE(0x114, 0xf)
  DPP_ADD_STAGE(0x118, 0xf)
  DPP_ADD_STAGE(0x142, 0xa)
  DPP_ADD_STAGE(0x143, 0xc)
#undef DPP_ADD_STAGE
  return v;
}

#define PIN7(QB)                                                               \
  asm volatile("" : "+v"(QB[0]), "+v"(QB[1]), "+v"(QB[2]), "+v"(QB[3]),        \
                    "+v"(QB[4]), "+v"(QB[5]), "+v"(QB[6]));

// NT loads for group G (rows 1+7G..7+7G, clamped).
#define PREFETCH(QB, G)                                                        \
  {                                                                            \
    int tp = 1 + 7 * (G);                                                      \
    _Pragma("unroll") for (int j = 0; j < 7; ++j) {                            \
      int r = tp + j;                                                          \
      r = r > 719 ? 719 : r;                                                   \
      QB[j] = __builtin_nontemporal_load(&train[r * B_DIM + bc]);              \
    }                                                                          \
  }

// ---- wave0 (producer): divides + recurrence, results to LDS double-buffer.
#define W0C(QB, NS)                                                            \
  {                                                                            \
    float xds[7], nlv[7];                                                      \
    _Pragma("unroll") for (int j = 0; j < (NS); ++j)                           \
        xds[j] = __fdividef(QB[j], buf[j]);                                    \
    nlv[0] = fmaf(lsm, xds[0], olm * lev);                                     \
    _Pragma("unroll") for (int j = 1; j < (NS); ++j)                           \
        nlv[j] = fmaf(lsm, xds[j], olm * nlv[j - 1]);                          \
    _Pragma("unroll") for (int j = 0; j < (NS); ++j)                           \
        buf[j] = fmaf(ssm, __fdividef(QB[j], nlv[j]), osm * buf[j]);           \
    _Pragma("unroll") for (int j = 0; j < (NS); ++j) {                         \
      v2f p;                                                                   \
      p.x = nlv[j];                                                            \
      p.y = buf[j];                                                            \
      dbuf[g & 1][j][lane] = p;                                                \
    }                                                                          \
    lev = nlv[(NS)-1];                                                         \
    ++g;                                                                       \
  }

// ---- wave1 (consumer): logs, output stores, sq-diffs, DPP, strip.
#define W1P(NS)                                                                \
  {                                                                            \
    float nl[7], nsv[7], llv[7], sqv[7];                                       \
    _Pragma("unroll") for (int j = 0; j < (NS); ++j) {                         \
      v2f p = dbuf[qcnt & 1][j][lane];                                         \
      nl[j] = p.x;                                                             \
      nsv[j] = p.y;                                                            \
    }                                                                          \
    _Pragma("unroll") for (int j = 0; j < (NS); ++j)                           \
        llv[j] = __log2f(nl[j]);                                               \
    if (valid) {                                                               \
      _Pragma("unroll") for (int j = 0; j < (NS); ++j) {                       \
        *(float*)(lbase + boff + (unsigned)(j * B_DIM * 4)) = nl[j];           \
        *(float*)(sbase + boff + (unsigned)(j * B_DIM * 4)) = nsv[j];          \
      }                                                                        \
    }                                                                          \
    boff += (NS)*B_DIM * 4;                                                    \
    {                                                                          \
      float ld0 = llv[0] - llev;                                               \
      float d0 = ld0 - pld;                                                    \
      sqv[0] = valid ? d0 * d0 : 0.0f;                                         \
      float ldp = ld0;                                                         \
      _Pragma("unroll") for (int j = 1; j < (NS); ++j) {                       \
        float ld = llv[j] - llv[j - 1];                                        \
        float d = ld - ldp;                                                    \
        sqv[j] = valid ? d * d : 0.0f;                                         \
        ldp = ld;                                                              \
      }                                                                        \
      pld = ldp;                                                               \
    }                                                                          \
    llev = llv[(NS)-1];                                                        \
    _Pragma("unroll") for (int j = 0; j < (NS); ++j)                           \
        sqv[j] = dpp_sum64(sqv[j]);                                            \
    if (lane == 63) {                                                          \
      int tb = 1 + 7 * qcnt;                                                   \
      _Pragma("unroll") for (int j = 0; j < (NS); ++j)                         \
          lds_p[tb + j - 1] = sqv[j];                                          \
    }                                                                          \
    ++qcnt;                                                                    \
  }

__global__ __launch_bounds__(128) void esrnn_main(
    const float* __restrict__ train, const float* __restrict__ lev_sms,
    const float* __restrict__ seas_sms, const float* __restrict__ init_seas_in,
    float* __restrict__ levs_out, float* __restrict__ seas_out,
    float* __restrict__ partial) {
  __shared__ v2f dbuf[2][7][64];
  __shared__ float lds_p[720];

  int tid = threadIdx.x;
  int lane = tid & 63;
  int w = tid >> 6;  // 0 = producer wave, 1 = consumer wave
  int wid = blockIdx.x;
  int b = wid * 64 + lane;
  bool valid = (b < B_DIM);
  int bc = valid ? b : (B_DIM - 1);

  // producer state
  float lsm = 0, olm = 0, ssm = 0, osm = 0, lev = 0;
  float buf[7];
  float xa[7], xb[7], xc[7], xd[7];
  int g = 0;
  // consumer state
  float llev = 0, pld = 0;
  unsigned boff = 0;
  int qcnt = 0;
  char* lbase = (char*)levs_out + (size_t)B_DIM * 4;
  char* sbase = (char*)seas_out + (size_t)8 * B_DIM * 4;

  if (w == 0) {
    lsm = 1.0f / (1.0f + __expf(-lev_sms[bc]));
    ssm = 1.0f / (1.0f + __expf(-seas_sms[bc]));
    olm = 1.0f - lsm;
    osm = 1.0f - ssm;
    float is[7];
#pragma unroll
    for (int j = 0; j < 7; ++j) is[j] = __expf(init_seas_in[bc * 7 + j]);
    lev = __fdividef(train[bc], is[0]);
#pragma unroll
    for (int j = 0; j < 6; ++j) buf[j] = is[j + 1];
    buf[6] = is[0];
    PREFETCH(xa, 0)
    PREFETCH(xb, 1)
    PREFETCH(xc, 2)
  } else {
    float is[7];
#pragma unroll
    for (int j = 0; j < 7; ++j) is[j] = __expf(init_seas_in[bc * 7 + j]);
    float lev0 = __fdividef(train[bc], is[0]);
    llev = __log2f(lev0);
    pld = 0.0f;
    boff = (unsigned)b * 4u;
    if (valid) {
      levs_out[b] = lev0;
#pragma unroll
      for (int j = 0; j < 7; ++j) seas_out[j * B_DIM + b] = is[j];
      seas_out[7 * B_DIM + b] = is[0];
    }
  }

  // k = 0: producer computes group 0; consumer idle.
  if (w == 0) {
    PREFETCH(xd, 3)
    PIN7(xb)
    W0C(xa, 7)
  }
  __syncthreads();

  // k = 1..100 (25 x 4): steady-state pipeline.
  for (int kk = 0; kk < 25; ++kk) {
    if (w == 0) { PREFETCH(xa, g + 3) PIN7(xc) W0C(xb, 7) } else { W1P(7) }
    __syncthreads();
    if (w == 0) { PREFETCH(xb, g + 3) PIN7(xd) W0C(xc, 7) } else { W1P(7) }
    __syncthreads();
    if (w == 0) { PREFETCH(xc, g + 3) PIN7(xa) W0C(xd, 7) } else { W1P(7) }
    __syncthreads();
    if (w == 0) { PREFETCH(xd, g + 3) PIN7(xb) W0C(xa, 7) } else { W1P(7) }
    __syncthreads();
  }
  // k = 101: producer group 101 (in xb); consumer group 100.
  if (w == 0) { PIN7(xc) W0C(xb, 7) } else { W1P(7) }
  __syncthreads();
  // k = 102: producer tail group 102 (5 steps, in xc); consumer group 101.
  if (w == 0) { W0C(xc, 5) } else { W1P(7) }
  __syncthreads();
  // k = 103: consumer tail group 102.
  if (w == 1) { W1P(5) }
  __syncthreads();

  // Flush per-wave strip (wave-major layout), both waves cooperate.
  for (int i = tid; i < N_MSLD; i += 128)
    partial[(size_t)wid * N_MSLD + i] = lds_p[i + 1];
}

__global__ __launch_bounds__(64) void esrnn_reduce2(
    const float* __restrict__ partial, float* __restrict__ msld) {
  int row = blockIdx.x;  // 0..717
  int lane = threadIdx.x;
  float s = 0.0f;
  for (int i = lane; i < NW; i += 64) s += partial[(size_t)i * N_MSLD + row];
  float tot = dpp_sum64(s);
  if (lane == 63) msld[row] = tot * (LN2_SQ / (float)B_DIM);
}

extern "C" void kernel_launch(void* const* d_in, const int* in_sizes, int n_in,
                              void* d_out, int out_size, void* d_ws,
                              size_t ws_size, hipStream_t stream) {
  const float* train = (const float*)d_in[0];
  const float* lev_sms = (const float*)d_in[1];
  const float* seas_sms = (const float*)d_in[2];
  const float* init_seas = (const float*)d_in[3];

  float* out = (float*)d_out;
  float* levs = out;
  float* seas = out + OFF_SEAS;
  float* msld = out + OFF_MSLD;
  float* partial = (float*)d_ws;  // NW*718*4 ~= 2.25 MB, wave-major

  esrnn_main<<<NBLK, 128, 0, stream>>>(train, lev_sms, seas_sms, init_seas,
                                       levs, seas, partial);
  esrnn_reduce2<<<N_MSLD, 64, 0, stream>>>(partial, msld);
}